// Round 6
// baseline (364.004 us; speedup 1.0000x reference)
//
#include <hip/hip_runtime.h>
#include <hip/hip_cooperative_groups.h>

namespace cg = cooperative_groups;

// VQ-VAE forward: out = code_out[argmax_c(logits_c(x))], hard_idx = argmax.
// logits are piecewise-linear in scalar x (128 relu breakpoints). Build the
// per-interval UPPER ENVELOPE of the 512 affine logit lines (fp64-exact,
// branchless pairwise L/U-bound formulation), flatten to one global x-sorted
// segment table + 4096-bucket accelerator, then O(1) per-sample lookup.
// R6: entire pipeline in ONE cooperative kernel (7 launches -> 1); phases
// separated by grid.sync(). Math identical to R5 (absmax==0 twice).

#define B_SAMPLES 262144
#define HIDDEN    128
#define NUM_CODES 512
#define EMBED_DIM 256
#define NUM_INT   129     // HIDDEN + 1 intervals
#define MAXSEG    (NUM_INT * NUM_CODES)
#define NBUCK     4096
#define NBLK      512     // 2 blocks/CU, co-resident (cooperative)

// ---- workspace layout (byte offsets) ----
// 0       : t_sorted[128] double
// 2048    : code_out[512] double
// 8192    : env_cnt[129] int
// 12288   : gM[1] int
// 16384   : gbuck[4097] int
// 36864   : surv[MAXSEG] uchar
// 106496  : Lx[MAXSEG] double
// 638976  : AB[MAXSEG] double2
// 1703936 : env_xs[MAXSEG] double
// 2236416 : env_idx[MAXSEG] int
// 2502656 : gxs[MAXSEG] double
// 3031040 : gval[MAXSEG] float2      -> total ~3.6 MB

struct TabS {   // phase 0
  double tloc[HIDDEN], ts[HIDDEN], wj[HIDDEN], bj[HIDDEN], sdw[EMBED_DIM];
};
struct EnvS {   // phase 1   (17408 B = union max)
  double2 sAB[NUM_CODES];
  double nl[4][64], dl[4][64], nu[4][64], du[4][64];
  int dd[4][64];
};
struct CmpS { double sA[NUM_CODES]; };                       // phase 2
struct Kg2S { int scount[NUM_INT], sj0[NUM_INT], soff[NUM_INT + 1]; }; // phase 3
union SMem { TabS t; EnvS e; CmpS c; Kg2S g; };

__global__ void __launch_bounds__(256, 2) k_all(
    const float* __restrict__ x,   const float* __restrict__ w1,
    const float* __restrict__ b1,  const float* __restrict__ w2,
    const float* __restrict__ b2,  const float* __restrict__ emb,
    const float* __restrict__ decw, const float* __restrict__ decb,
    double* __restrict__ t_sorted, double* __restrict__ code_out,
    int* __restrict__ env_cnt, int* __restrict__ gM, int* __restrict__ gbuck,
    unsigned char* __restrict__ surv, double* __restrict__ Lx,
    double2* __restrict__ AB, double* __restrict__ env_xs,
    int* __restrict__ env_idx, double* __restrict__ gxs,
    float2* __restrict__ gval, float* __restrict__ out,
    float* __restrict__ idx_out) {
  cg::grid_group grid = cg::this_grid();
  __shared__ SMem sm;
  const int blk = blockIdx.x, tid = threadIdx.x;

  // ---------- phase 0: thresholds + AB tables + code_out + env_cnt zero ----
  if (blk < 258) {                       // table task T = blk (interval, half)
    if (tid < HIDDEN) {
      double w = (double)w1[tid], b = (double)b1[tid];
      double t = -b / w;
      if (!isfinite(t)) t = 1e30;
      t = fmin(fmax(t, -1e30), 1e30);
      sm.t.tloc[tid] = t;
    }
    __syncthreads();
    if (tid < HIDDEN) {                  // stable rank sort, O(128^2)
      double t = sm.t.tloc[tid];
      int r = 0;
      for (int k = 0; k < HIDDEN; ++k) {
        double tk = sm.t.tloc[k];
        r += (tk < t) || (tk == t && k < tid);
      }
      sm.t.ts[r] = t;
    }
    __syncthreads();
    if (blk == 0 && tid < HIDDEN) t_sorted[tid] = sm.t.ts[tid];
    const int i = blk >> 1;
    const int c = ((blk & 1) << 8) + tid;
    double xm;
    if (i == 0)           xm = sm.t.ts[0] - 1.0;
    else if (i == HIDDEN) xm = sm.t.ts[HIDDEN - 1] + 1.0;
    else                  xm = 0.5 * (sm.t.ts[i - 1] + sm.t.ts[i]);
    if (tid < HIDDEN) {
      double w = (double)w1[tid], b = (double)b1[tid];
      bool act = fma(w, xm, b) > 0.0;    // relu sign constant in open interval
      sm.t.wj[tid] = act ? w : 0.0;
      sm.t.bj[tid] = act ? b : 0.0;
    }
    __syncthreads();
    const float4* r4 = (const float4*)(w2 + c * HIDDEN);
    double A = 0.0, Bv = 0.0;
    #pragma unroll 8
    for (int q = 0; q < HIDDEN / 4; ++q) {
      const float4 v = r4[q];
      const int j = q * 4;
      A  = fma((double)v.x, sm.t.wj[j + 0], A);
      A  = fma((double)v.y, sm.t.wj[j + 1], A);
      A  = fma((double)v.z, sm.t.wj[j + 2], A);
      A  = fma((double)v.w, sm.t.wj[j + 3], A);
      Bv = fma((double)v.x, sm.t.bj[j + 0], Bv);
      Bv = fma((double)v.y, sm.t.bj[j + 1], Bv);
      Bv = fma((double)v.z, sm.t.bj[j + 2], Bv);
      Bv = fma((double)v.w, sm.t.bj[j + 3], Bv);
    }
    AB[(i << 9) + c] = make_double2(A, Bv + (double)b2[c]);
  } else if (blk < 260) {                // code_out, 2 blocks x 256 codes
    sm.t.sdw[tid] = (double)decw[tid];
    __syncthreads();
    const int c = (blk - 258) * 256 + tid;
    const float4* e4 = (const float4*)(emb + c * EMBED_DIM);
    double s = 0.0;
    #pragma unroll 8
    for (int q = 0; q < EMBED_DIM / 4; ++q) {
      const float4 v = e4[q];
      const int j = q * 4;
      s = fma((double)v.x, sm.t.sdw[j + 0], s);
      s = fma((double)v.y, sm.t.sdw[j + 1], s);
      s = fma((double)v.z, sm.t.sdw[j + 2], s);
      s = fma((double)v.w, sm.t.sdw[j + 3], s);
    }
    code_out[c] = s + (double)decb[0];
  } else if (blk == 260) {
    if (tid < NUM_INT) env_cnt[tid] = 0;
  }
  grid.sync();

  // ---------- phase 1: branchless pairwise envelope membership --------------
  // L as (nL,dL) dL>=0 (dL==0 => -inf); U as (nU,dU) dU<=0 (dU==0 => +inf).
  for (int T = blk; T < NUM_INT * 8; T += NBLK) {
    const int i = T >> 3, g = T & 7;
    const int w = tid >> 6, lane = tid & 63;
    const int c = (g << 6) + lane;
    __syncthreads();                     // protect LDS reuse across iterations
    const double2* row = AB + (i << 9);
    for (int t = tid; t < NUM_CODES; t += 256) sm.e.sAB[t] = row[t];
    __syncthreads();
    const double2 my = sm.e.sAB[c];
    double nL = -1.0, dL = 0.0, nU = -1.0, dU = 0.0;
    int dead = 0;
    const int k0 = w << 7;
    #pragma unroll 4
    for (int kk = 0; kk < 128; ++kk) {
      const int k = k0 + kk;
      const double2 o = sm.e.sAB[k];     // wave-uniform -> LDS broadcast
      const double d = my.x - o.x;
      const double n = o.y - my.y;       // x* = n/d
      const bool cL = (d > 0.0) && (n * dL > nL * d);
      const bool cU = (d < 0.0) && (n * dU < nU * d);
      nL = cL ? n : nL;  dL = cL ? d : dL;
      nU = cU ? n : nU;  dU = cU ? d : dU;
      dead |= (d == 0.0) && ((n > 0.0) || (n == 0.0 && k < c));
    }
    sm.e.nl[w][lane] = nL; sm.e.dl[w][lane] = dL;
    sm.e.nu[w][lane] = nU; sm.e.du[w][lane] = dU;
    sm.e.dd[w][lane] = dead;
    __syncthreads();
    if (tid < 64) {                      // wave 0 merges the 4 k-chunks
      #pragma unroll
      for (int wv = 1; wv < 4; ++wv) {
        double cn = sm.e.nl[wv][lane], cd = sm.e.dl[wv][lane];
        if (cn * dL > nL * cd) { nL = cn; dL = cd; }
        cn = sm.e.nu[wv][lane]; cd = sm.e.du[wv][lane];
        if (cn * dU < nU * cd) { nU = cn; dU = cd; }
        dead |= sm.e.dd[wv][lane];
      }
      const int sv = (!dead) && (dL == 0.0 || dU == 0.0 || (nL * dU > nU * dL));
      const int pair = (i << 9) + c;
      surv[pair] = (unsigned char)sv;
      Lx[pair]   = (dL == 0.0) ? -1e300 : nL / dL;
      const unsigned long long m = __ballot(sv);
      if (lane == 0) atomicAdd(&env_cnt[i], (int)__popcll(m));
    }
  }
  grid.sync();

  // ---------- phase 2: compact survivors, slope-sorted ----------------------
  for (int T = blk; T < 258; T += NBLK) {
    const int i = T >> 1;
    const int c = ((T & 1) << 8) + tid;
    const int base = i << 9;
    __syncthreads();
    for (int t = tid; t < NUM_CODES; t += 256)
      sm.c.sA[t] = surv[base + t] ? AB[base + t].x : 1e300;
    __syncthreads();
    const double myA = sm.c.sA[c];
    int rank = 0;
    #pragma unroll 8
    for (int k = 0; k < NUM_CODES; ++k) rank += (sm.c.sA[k] < myA) ? 1 : 0;
    if (surv[base + c]) {
      env_xs[base + rank]  = Lx[base + c];
      env_idx[base + rank] = c;
    }
  }
  grid.sync();

  // ---------- phase 3: flatten to global x-sorted table ---------------------
  if (blk < NUM_INT) {
    if (tid < NUM_INT) {
      const int ii = tid;
      const double tlo = (ii == 0) ? -1e300 : t_sorted[ii - 1];
      const double thi = (ii == NUM_INT - 1) ? 1e300 : t_sorted[ii];
      const int cnt = env_cnt[ii];
      const int base = ii << 9;
      int lo = 0, hi = cnt - 1;          // j0: largest j with xs <= tlo
      while (lo < hi) { int mid = (lo + hi + 1) >> 1; if (env_xs[base + mid] <= tlo) lo = mid; else hi = mid - 1; }
      const int j0 = lo;
      lo = 0; hi = cnt - 1;              // jend: largest j with xs < thi
      while (lo < hi) { int mid = (lo + hi + 1) >> 1; if (env_xs[base + mid] < thi) lo = mid; else hi = mid - 1; }
      sm.g.sj0[ii] = j0;
      sm.g.scount[ii] = max(0, lo - j0 + 1);   // 0 for zero-width intervals
    }
    __syncthreads();
    if (tid <= NUM_INT) sm.g.soff[tid] = (tid == 0) ? 0 : sm.g.scount[tid - 1];
    __syncthreads();
    for (int off = 1; off <= NUM_INT; off <<= 1) {   // Hillis-Steele prefix
      int v = 0;
      if (tid <= NUM_INT && tid >= off) v = sm.g.soff[tid - off];
      __syncthreads();
      if (tid <= NUM_INT) sm.g.soff[tid] += v;
      __syncthreads();
    }
    const int i = blk;
    const int off = sm.g.soff[i], j0 = sm.g.sj0[i], cnt_i = sm.g.scount[i];
    const int base = i << 9;
    const double tlo = (i == 0) ? -1e300 : t_sorted[i - 1];
    for (int k = tid; k < cnt_i; k += 256) {
      const int c = env_idx[base + j0 + k];
      gxs[off + k]  = (k == 0) ? tlo : env_xs[base + j0 + k];
      gval[off + k] = make_float2((float)code_out[c], (float)c);
    }
    if (i == 0 && tid == 0) gM[0] = sm.g.soff[NUM_INT];
  }
  grid.sync();

  // ---------- phase 4: bucket accelerator -----------------------------------
  if (blk < NBUCK / 256) {
    const int b = blk * 256 + tid;
    const int M = gM[0];
    const unsigned key = (unsigned)b << 20;
    const unsigned u = (key & 0x80000000u) ? (key ^ 0x80000000u) : ~key;
    const float xf = __uint_as_float(u);
    double xb;
    if (xf != xf) xb = (b >= NBUCK / 2) ? 1e300 : -1e300;  // NaN-prefix buckets
    else          xb = (double)xf;
    int lo = 0, hi = M - 1;
    while (lo < hi) { int mid = (lo + hi + 1) >> 1; if (gxs[mid] <= xb) lo = mid; else hi = mid - 1; }
    gbuck[b] = lo;
    if (b == 0) gbuck[NBUCK] = M - 1;
  }
  grid.sync();

  // ---------- phase 5: per-sample lookup (2 samples/thread, float2 I/O) -----
  {
    const int s = blk * 512 + tid * 2;
    const float2 xv2 = *(const float2*)(x + s);
    const float xs2[2] = {xv2.x, xv2.y};
    float o[2], id[2];
    #pragma unroll
    for (int k = 0; k < 2; ++k) {
      const float xf = xs2[k];
      const double xv = (double)xf;
      const unsigned u = __float_as_uint(xf);
      const unsigned key = (u & 0x80000000u) ? ~u : (u | 0x80000000u);
      const int b = key >> 20;
      int lo = gbuck[b], hi = gbuck[b + 1];
      while (lo < hi) {                  // rare: bucket spans >1 segment
        const int mid = (lo + hi + 1) >> 1;
        if (gxs[mid] <= xv) lo = mid; else hi = mid - 1;
      }
      const float2 v = gval[lo];
      o[k] = v.x; id[k] = v.y;
    }
    *(float2*)(out + s)     = make_float2(o[0], o[1]);
    *(float2*)(idx_out + s) = make_float2(id[0], id[1]);
  }
}

extern "C" void kernel_launch(void* const* d_in, const int* in_sizes, int n_in,
                              void* d_out, int out_size, void* d_ws, size_t ws_size,
                              hipStream_t stream) {
  const float* x    = (const float*)d_in[0];
  const float* w1   = (const float*)d_in[1];
  const float* b1   = (const float*)d_in[2];
  const float* w2   = (const float*)d_in[3];
  const float* b2   = (const float*)d_in[4];
  const float* emb  = (const float*)d_in[5];
  const float* decw = (const float*)d_in[6];
  const float* decb = (const float*)d_in[7];

  char* ws = (char*)d_ws;
  double*        t_sorted = (double*)        (ws + 0);
  double*        code_out = (double*)        (ws + 2048);
  int*           env_cnt  = (int*)           (ws + 8192);
  int*           gM       = (int*)           (ws + 12288);
  int*           gbuck    = (int*)           (ws + 16384);
  unsigned char* surv     = (unsigned char*) (ws + 36864);
  double*        Lx       = (double*)        (ws + 106496);
  double2*       AB       = (double2*)       (ws + 638976);
  double*        env_xs   = (double*)        (ws + 1703936);
  int*           env_idx  = (int*)           (ws + 2236416);
  double*        gxs      = (double*)        (ws + 2502656);
  float2*        gval     = (float2*)        (ws + 3031040);

  float* out  = (float*)d_out;
  float* idxo = out + B_SAMPLES;

  void* args[] = {
    (void*)&x, (void*)&w1, (void*)&b1, (void*)&w2, (void*)&b2, (void*)&emb,
    (void*)&decw, (void*)&decb, (void*)&t_sorted, (void*)&code_out,
    (void*)&env_cnt, (void*)&gM, (void*)&gbuck, (void*)&surv, (void*)&Lx,
    (void*)&AB, (void*)&env_xs, (void*)&env_idx, (void*)&gxs, (void*)&gval,
    (void*)&out, (void*)&idxo
  };
  hipLaunchCooperativeKernel((const void*)k_all, dim3(NBLK), dim3(256),
                             args, 0, stream);
}